// Round 13
// baseline (238.573 us; speedup 1.0000x reference)
//
#include <hip/hip_runtime.h>
#include <math.h>
#include <float.h>

// Problem constants (fixed by the reference)
#define Bn   64
#define Sn   512
#define FWn  6
#define Wn   507     // S - FW + 1
#define WT   32      // windows per block (2 sub-tiles of 16) — R12 geometry
#define NTILE 16     // 507 windows -> 16 tiles of 32

#define PROWS   37    // projection rows per block (32 windows + FW-1)
#define PSTRIDE 512   // fp16 elems per Pt row (1024 B); phase-conflict-free (R10)

#define LOG2E  1.4426950408889634f
#define LOG2E2 2.8853900817779268f

typedef __attribute__((ext_vector_type(8))) _Float16 half8;
typedef __attribute__((ext_vector_type(4))) _Float16 half4;
typedef __attribute__((ext_vector_type(4))) float f32x4;

// ---------------------------------------------------------------------------
// Kernel 0: pack w_ih and w_hh into fp16 B-fragment order for
// mfma_f32_16x16x32_f16, PRE-SCALED by log2e (gates i,f,o) / 2log2e (gate g).
// Vectorized: 4 elems/thread (float4 in, half4 out). 16384 threads = 64 blocks
// (R19's 128-block overrun bug fixed in R20 — grid MUST be 64).
// Also zero-inits featk (8192 keys) + cnt (64 counters) — no extra launch.
// ---------------------------------------------------------------------------
__global__ void __launch_bounds__(256)
pack_w_kernel(const float* __restrict__ w_ih, const float* __restrict__ w_hh,
              _Float16* __restrict__ wih_p, _Float16* __restrict__ whh_p,
              unsigned* __restrict__ featk)
{
    const int i4 = blockIdx.x * 256 + threadIdx.x;   // 0..16383 (4 elems each)
    if (i4 < Bn * 128 + Bn) featk[i4] = 0;           // featk floor + cnt zero
    const int e  = i4 * 4;                           // 0..65532
    const int j0 = e & 4;
    const int L  = (e >> 3) & 63;
    const int ks = (e >> 9) & 3;
    const int nt = e >> 11;                          // 0..31
    const int row = nt * 16 + (L & 15);
    const int col = ks * 32 + (L >> 4) * 8 + j0;
    const float sc = ((nt >> 3) == 2) ? LOG2E2 : LOG2E;   // gate g doubled
    float4 a = *(const float4*)(w_ih + row * 128 + col);
    float4 b = *(const float4*)(w_hh + row * 128 + col);
    half4 pa, pb;
    pa[0] = (_Float16)(sc * a.x); pa[1] = (_Float16)(sc * a.y);
    pa[2] = (_Float16)(sc * a.z); pa[3] = (_Float16)(sc * a.w);
    pb[0] = (_Float16)(sc * b.x); pb[1] = (_Float16)(sc * b.y);
    pb[2] = (_Float16)(sc * b.z); pb[3] = (_Float16)(sc * b.w);
    *(half4*)(wih_p + e) = pa;
    *(half4*)(whh_p + e) = pb;
}

// ---------------------------------------------------------------------------
// Kernel 1 (fused MFMA LSTM + fused FC epilogue).
//   Body = R15's verified-best lstm (58 us; streamed whh at the allocator's
//   64-VGPR pin, 3 blocks/CU, fused exp2 activations).
//   R21: final_kernel FUSED — after the atomicMax fold into featk, each
//   block does threadfence + atomicAdd(cnt[b]); the LAST of b's 16 tile-
//   blocks re-reads the 128 keys via atomicOr(p,0) (device-coherent read;
//   plain loads may hit a stale per-XCD L2 line) and computes out[b][0:2].
//   No spinning -> no deadlock; dispatch-order independent; graph-safe.
//   FC scratch reuses DEAD hsA LDS — total stays exactly 54272 B (adding
//   even 32 B would round past the 3-blocks/CU LDS boundary).
// grid 64*16, block 512.
// ---------------------------------------------------------------------------
__global__ void __launch_bounds__(512)
__attribute__((amdgpu_waves_per_eu(4, 4)))
lstm_kernel(const int* __restrict__ inputs, const float* __restrict__ embed,
            const _Float16* __restrict__ wih_p, const _Float16* __restrict__ whh_p,
            const float* __restrict__ b_ih, const float* __restrict__ b_hh,
            unsigned* __restrict__ featk, unsigned* __restrict__ cnt,
            const float* __restrict__ fc_w, const float* __restrict__ fc_b,
            float* __restrict__ out)
{
    __shared__ __align__(16) _Float16 Pt[PROWS * PSTRIDE];  // 37 KiB
    __shared__ __align__(16) _Float16 hsA[2][2][2048];      // 16 KiB
    const int t    = threadIdx.x;
    const int L    = t & 63;
    const int ut   = t >> 6;          // wave index = unit-tile 0..7
    const int b    = blockIdx.x >> 4;
    const int tile = blockIdx.x & 15;
    const int w0   = tile * WT;
    const int q  = L >> 4;
    const int ln = L & 15;
    const int j8 = L & 7;
    const int u  = ut * 16 + ln;      // this lane's hidden unit (B n-index)

    // ---- phase 1: x-proj (3 m-tiles = rows 0..47, stores clamped to 37) ----
    {
        f32x4 accx[3][4];   // [mt][gate], init with folded bias
#pragma unroll
        for (int g = 0; g < 4; ++g) {
            const float sc = (g == 2) ? LOG2E2 : LOG2E;
            const float bg = sc * (b_ih[g * 128 + u] + b_hh[g * 128 + u]);
            accx[0][g] = (f32x4){bg, bg, bg, bg};
            accx[1][g] = accx[0][g];
            accx[2][g] = accx[0][g];
        }
        int tok[3];
#pragma unroll
        for (int mt = 0; mt < 3; ++mt) {
            int s = w0 + mt * 16 + ln; s = s < 511 ? s : 511;  // clamp (masked at max)
            tok[mt] = inputs[b * Sn + s];
        }
#pragma unroll
        for (int ks = 0; ks < 4; ++ks) {
            half8 ax[3];
#pragma unroll
            for (int mt = 0; mt < 3; ++mt) {
                const float* er = embed + (size_t)tok[mt] * 128 + ks * 32 + q * 8;
                float4 e0 = *(const float4*)er;
                float4 e1 = *(const float4*)(er + 4);
                half8 a;
                a[0] = (_Float16)e0.x; a[1] = (_Float16)e0.y;
                a[2] = (_Float16)e0.z; a[3] = (_Float16)e0.w;
                a[4] = (_Float16)e1.x; a[5] = (_Float16)e1.y;
                a[6] = (_Float16)e1.z; a[7] = (_Float16)e1.w;
                ax[mt] = a;
            }
#pragma unroll
            for (int g = 0; g < 4; ++g) {
                half8 bw = *(const half8*)(wih_p + ((size_t)((g * 8 + ut) * 4 + ks) * 64 + L) * 8);
#pragma unroll
                for (int mt = 0; mt < 3; ++mt)
                    accx[mt][g] = __builtin_amdgcn_mfma_f32_16x16x32_f16(ax[mt], bw, accx[mt][g], 0, 0, 0);
            }
        }
        // store gate-interleaved fp16 Pt rows (predicated to 37 rows)
#pragma unroll
        for (int mt = 0; mt < 3; ++mt)
#pragma unroll
            for (int r = 0; r < 4; ++r) {
                const int sl = mt * 16 + q * 4 + r;
                if (sl < PROWS) {
                    half4 o;
                    o[0] = (_Float16)accx[mt][0][r];
                    o[1] = (_Float16)accx[mt][1][r];
                    o[2] = (_Float16)accx[mt][2][r];
                    o[3] = (_Float16)accx[mt][3][r];
                    *(half4*)&Pt[sl * PSTRIDE + u * 4] = o;
                }
            }
    }

    // w_hh B-fragments, source-hoisted (allocator streams from L2 at its
    // 64-VGPR pin — benched fastest across R12..R18).
    half8 whf[4][4];    // [gate][ks]
#pragma unroll
    for (int g = 0; g < 4; ++g)
#pragma unroll
        for (int ks = 0; ks < 4; ++ks)
            whf[g][ks] = *(const half8*)(whh_p + ((size_t)((g * 8 + ut) * 4 + ks) * 64 + L) * 8);

    __syncthreads();    // Pt visible to all waves

    // h scatter address components (A-fragment layout for unit u, window m)
    const int ks_h = ut >> 1;
    const int qp   = (ut & 1) * 2 + (ln >> 3);

    float cst[2][4] = {{0.f, 0.f, 0.f, 0.f}, {0.f, 0.f, 0.f, 0.f}};
    float mv = -FLT_MAX;

    // ---- steps 0..5, two independent sub-tiles per barrier interval ----
    for (int st = 0; st < FWn; ++st) {
        if (st > 0) __syncthreads();        // prev step's h scatter visible
#pragma unroll
        for (int sub = 0; sub < 2; ++sub) {
            f32x4 acc[4];                   // [gate] over r
#pragma unroll
            for (int r = 0; r < 4; ++r) {
                half4 pv = *(const half4*)&Pt[(sub * 16 + q * 4 + r + st) * PSTRIDE + u * 4];
                acc[0][r] = (float)pv[0]; acc[1][r] = (float)pv[1];
                acc[2][r] = (float)pv[2]; acc[3][r] = (float)pv[3];
            }
            if (st > 0) {
                const _Float16* hb = hsA[(st + 1) & 1][sub];   // h(st-1)
#pragma unroll
                for (int ks = 0; ks < 4; ++ks) {
                    half8 ah = *(const half8*)(hb + (ks * 64 + L) * 8);
#pragma unroll
                    for (int g = 0; g < 4; ++g)
                        acc[g] = __builtin_amdgcn_mfma_f32_16x16x32_f16(ah, whf[g][ks], acc[g], 0, 0, 0);
                }
            }
            _Float16* buf = hsA[st & 1][sub];
#pragma unroll
            for (int r = 0; r < 4; ++r) {
                // pre-activations already scaled: i',f',o' by log2e; g'' by 2log2e
                float a  = __builtin_amdgcn_exp2f(-acc[0][r]);   // exp(-i)
                float cf = __builtin_amdgcn_exp2f(-acc[1][r]);   // exp(-f)
                float bb = __builtin_amdgcn_exp2f(-acc[2][r]);   // exp(-2g)
                float co = __builtin_amdgcn_exp2f(-acc[3][r]);   // exp(-o)
                float ft  = __builtin_amdgcn_rcpf(1.0f + cf);                    // sig(f)
                float itg = (1.0f - bb) * __builtin_amdgcn_rcpf((1.0f + a) * (1.0f + bb)); // sig(i)*tanh(g)
                float cc  = fmaf(cst[sub][r], ft, itg);
                cst[sub][r] = cc;
                float d  = __builtin_amdgcn_exp2f(-LOG2E2 * cc);                 // exp(-2c)
                float hv = (1.0f - d) * __builtin_amdgcn_rcpf((1.0f + co) * (1.0f + d));   // sig(o)*tanh(c)
                if (st < FWn - 1) {
                    buf[ks_h * 512 + (qp * 16 + q * 4 + r) * 8 + j8] = (_Float16)hv;
                } else {
                    const int w = w0 + sub * 16 + q * 4 + r;
                    mv = fmaxf(mv, (w < Wn) ? hv : -FLT_MAX);
                }
            }
        }
    }

    // ---- reduce max across q; q==0 lanes atomically fold into feat[b][u] ----
    mv = fmaxf(mv, __shfl_xor(mv, 16));
    mv = fmaxf(mv, __shfl_xor(mv, 32));
    if (q == 0) {
        // order-preserving encode: monotone in float order, all real keys > 0
        unsigned bits = __float_as_uint(mv);
        unsigned key  = (bits & 0x80000000u) ? ~bits : (bits | 0x80000000u);
        atomicMax(featk + b * 128 + u, key);
    }

    // ---- fused FC epilogue: last tile-block of batch b does the 128->2 FC ----
    // Reuse dead hsA LDS for the tiny reduction scratch (LDS must stay 54272).
    float* red  = (float*)hsA;           // red[0..3]
    int*   lastf = (int*)hsA + 4;
    __threadfence();                     // release: atomicMax visible before count
    __syncthreads();                     // all lanes' fold + fence done
    if (t == 0)
        *lastf = (atomicAdd(cnt + b, 1u) == NTILE - 1);
    __syncthreads();
    if (*lastf) {
        float v0 = 0.f, v1 = 0.f;
        if (t < 128) {
            // device-coherent read of other XCDs' atomicMax results
            unsigned key = atomicOr(featk + b * 128 + t, 0u);
            const float m = __uint_as_float((key & 0x80000000u) ? (key & 0x7FFFFFFFu) : ~key);
            v0 = m * fc_w[t];
            v1 = m * fc_w[128 + t];
#pragma unroll
            for (int off = 1; off < 64; off <<= 1) {
                v0 += __shfl_xor(v0, off);
                v1 += __shfl_xor(v1, off);
            }
        }
        __syncthreads();                 // red[] safe to overwrite (hsA dead)
        if (t < 128 && (t & 63) == 0) { red[(t >> 6) * 2] = v0; red[(t >> 6) * 2 + 1] = v1; }
        __syncthreads();
        if (t == 0) {
            out[b * 2 + 0] = red[0] + red[2] + fc_b[0];
            out[b * 2 + 1] = red[1] + red[3] + fc_b[1];
        }
    }
}

// ---------------------------------------------------------------------------
extern "C" void kernel_launch(void* const* d_in, const int* in_sizes, int n_in,
                              void* d_out, int out_size, void* d_ws, size_t ws_size,
                              hipStream_t stream)
{
    const int*   inputs = (const int*)d_in[0];
    // d_in[1] = lengths : unused by the reference
    const float* embed  = (const float*)d_in[2];
    const float* w_ih   = (const float*)d_in[3];
    const float* w_hh   = (const float*)d_in[4];
    const float* b_ih   = (const float*)d_in[5];
    const float* b_hh   = (const float*)d_in[6];
    const float* fc_w   = (const float*)d_in[7];
    const float* fc_b   = (const float*)d_in[8];
    float* out = (float*)d_out;

    // workspace: featk (8192 u32) | cnt (64 u32) | wih_p, whh_p (128 KiB each)
    unsigned* featk = (unsigned*)d_ws;
    unsigned* cnt   = featk + Bn * 128;
    _Float16* wih_p = (_Float16*)(cnt + Bn);
    _Float16* whh_p = wih_p + 65536;

    pack_w_kernel<<<dim3(64), 256, 0, stream>>>(w_ih, w_hh, wih_p, whh_p, featk);
    lstm_kernel<<<dim3(Bn * NTILE), 512, 0, stream>>>(inputs, embed, wih_p, whh_p,
                                                      b_ih, b_hh, featk, cnt,
                                                      fc_w, fc_b, out);
}

// Round 14
// 139.291 us; speedup vs baseline: 1.7128x; 1.7128x over previous
//
#include <hip/hip_runtime.h>
#include <math.h>
#include <float.h>

// Problem constants (fixed by the reference)
#define Bn   64
#define Sn   512
#define FWn  6
#define Wn   507     // S - FW + 1
#define WT   32      // windows per block (2 sub-tiles of 16) — R12 geometry
#define NTILE 16     // 507 windows -> 16 tiles of 32

#define PROWS   37    // projection rows per block (32 windows + FW-1)
#define PSTRIDE 512   // fp16 elems per Pt row (1024 B); phase-conflict-free (R10)

#define LOG2E  1.4426950408889634f
#define LOG2E2 2.8853900817779268f

typedef __attribute__((ext_vector_type(8))) _Float16 half8;
typedef __attribute__((ext_vector_type(4))) _Float16 half4;
typedef __attribute__((ext_vector_type(4))) float f32x4;

// ---------------------------------------------------------------------------
// Kernel 0: pack w_ih and w_hh into fp16 B-fragment order for
// mfma_f32_16x16x32_f16, PRE-SCALED by log2e (gates i,f,o) / 2log2e (gate g).
// Vectorized: 4 elems/thread (float4 in, half4 out). 16384 threads = 64 blocks
// (grid MUST be 64 — R19's 128-block overrun corrupted whh_p).
// Also zero-inits featk (8192 keys) + cnt (64 counters) — no extra launch.
// Visibility: end-of-kernel implicit release flushes these stores before
// lstm starts (stream order), so lstm's device atomics see the zeros.
// ---------------------------------------------------------------------------
__global__ void __launch_bounds__(256)
pack_w_kernel(const float* __restrict__ w_ih, const float* __restrict__ w_hh,
              _Float16* __restrict__ wih_p, _Float16* __restrict__ whh_p,
              unsigned* __restrict__ featk)
{
    const int i4 = blockIdx.x * 256 + threadIdx.x;   // 0..16383 (4 elems each)
    if (i4 < Bn * 128 + Bn) featk[i4] = 0;           // featk floor + cnt zero
    const int e  = i4 * 4;                           // 0..65532
    const int j0 = e & 4;
    const int L  = (e >> 3) & 63;
    const int ks = (e >> 9) & 3;
    const int nt = e >> 11;                          // 0..31
    const int row = nt * 16 + (L & 15);
    const int col = ks * 32 + (L >> 4) * 8 + j0;
    const float sc = ((nt >> 3) == 2) ? LOG2E2 : LOG2E;   // gate g doubled
    float4 a = *(const float4*)(w_ih + row * 128 + col);
    float4 b = *(const float4*)(w_hh + row * 128 + col);
    half4 pa, pb;
    pa[0] = (_Float16)(sc * a.x); pa[1] = (_Float16)(sc * a.y);
    pa[2] = (_Float16)(sc * a.z); pa[3] = (_Float16)(sc * a.w);
    pb[0] = (_Float16)(sc * b.x); pb[1] = (_Float16)(sc * b.y);
    pb[2] = (_Float16)(sc * b.z); pb[3] = (_Float16)(sc * b.w);
    *(half4*)(wih_p + e) = pa;
    *(half4*)(whh_p + e) = pb;
}

// ---------------------------------------------------------------------------
// Kernel 1 (fused MFMA LSTM + fused FC epilogue).
//   Body = R15's verified-best lstm (58 us).
//   R22: R21's fused-FC protocol WITHOUT __threadfence(). R21 post-mortem:
//   the agent-scope fence emits cross-XCD L2 writeback/invalidate per block
//   (1024x), serializing and trashing the whh L2 stream (58->166 us). It is
//   also unnecessary: featk/cnt are touched ONLY by device-scope atomics
//   (RMW at the device coherent point, m20), and the __syncthreads between
//   a block's atomicMax and its atomicAdd drains vmcnt (compiler emits
//   s_waitcnt vmcnt(0) before s_barrier) — atomics complete at the coherent
//   point before the counter increments. Last block reads via atomicOr(p,0).
//   No spinning -> no deadlock; dispatch-order independent; graph-safe.
// grid 64*16, block 512.
// ---------------------------------------------------------------------------
__global__ void __launch_bounds__(512)
__attribute__((amdgpu_waves_per_eu(4, 4)))
lstm_kernel(const int* __restrict__ inputs, const float* __restrict__ embed,
            const _Float16* __restrict__ wih_p, const _Float16* __restrict__ whh_p,
            const float* __restrict__ b_ih, const float* __restrict__ b_hh,
            unsigned* __restrict__ featk, unsigned* __restrict__ cnt,
            const float* __restrict__ fc_w, const float* __restrict__ fc_b,
            float* __restrict__ out)
{
    __shared__ __align__(16) _Float16 Pt[PROWS * PSTRIDE];  // 37 KiB
    __shared__ __align__(16) _Float16 hsA[2][2][2048];      // 16 KiB
    const int t    = threadIdx.x;
    const int L    = t & 63;
    const int ut   = t >> 6;          // wave index = unit-tile 0..7
    const int b    = blockIdx.x >> 4;
    const int tile = blockIdx.x & 15;
    const int w0   = tile * WT;
    const int q  = L >> 4;
    const int ln = L & 15;
    const int j8 = L & 7;
    const int u  = ut * 16 + ln;      // this lane's hidden unit (B n-index)

    // ---- phase 1: x-proj (3 m-tiles = rows 0..47, stores clamped to 37) ----
    {
        f32x4 accx[3][4];   // [mt][gate], init with folded bias
#pragma unroll
        for (int g = 0; g < 4; ++g) {
            const float sc = (g == 2) ? LOG2E2 : LOG2E;
            const float bg = sc * (b_ih[g * 128 + u] + b_hh[g * 128 + u]);
            accx[0][g] = (f32x4){bg, bg, bg, bg};
            accx[1][g] = accx[0][g];
            accx[2][g] = accx[0][g];
        }
        int tok[3];
#pragma unroll
        for (int mt = 0; mt < 3; ++mt) {
            int s = w0 + mt * 16 + ln; s = s < 511 ? s : 511;  // clamp (masked at max)
            tok[mt] = inputs[b * Sn + s];
        }
#pragma unroll
        for (int ks = 0; ks < 4; ++ks) {
            half8 ax[3];
#pragma unroll
            for (int mt = 0; mt < 3; ++mt) {
                const float* er = embed + (size_t)tok[mt] * 128 + ks * 32 + q * 8;
                float4 e0 = *(const float4*)er;
                float4 e1 = *(const float4*)(er + 4);
                half8 a;
                a[0] = (_Float16)e0.x; a[1] = (_Float16)e0.y;
                a[2] = (_Float16)e0.z; a[3] = (_Float16)e0.w;
                a[4] = (_Float16)e1.x; a[5] = (_Float16)e1.y;
                a[6] = (_Float16)e1.z; a[7] = (_Float16)e1.w;
                ax[mt] = a;
            }
#pragma unroll
            for (int g = 0; g < 4; ++g) {
                half8 bw = *(const half8*)(wih_p + ((size_t)((g * 8 + ut) * 4 + ks) * 64 + L) * 8);
#pragma unroll
                for (int mt = 0; mt < 3; ++mt)
                    accx[mt][g] = __builtin_amdgcn_mfma_f32_16x16x32_f16(ax[mt], bw, accx[mt][g], 0, 0, 0);
            }
        }
        // store gate-interleaved fp16 Pt rows (predicated to 37 rows)
#pragma unroll
        for (int mt = 0; mt < 3; ++mt)
#pragma unroll
            for (int r = 0; r < 4; ++r) {
                const int sl = mt * 16 + q * 4 + r;
                if (sl < PROWS) {
                    half4 o;
                    o[0] = (_Float16)accx[mt][0][r];
                    o[1] = (_Float16)accx[mt][1][r];
                    o[2] = (_Float16)accx[mt][2][r];
                    o[3] = (_Float16)accx[mt][3][r];
                    *(half4*)&Pt[sl * PSTRIDE + u * 4] = o;
                }
            }
    }

    // w_hh B-fragments, source-hoisted (allocator streams from L2 at its
    // 64-VGPR pin — benched fastest across R12..R18).
    half8 whf[4][4];    // [gate][ks]
#pragma unroll
    for (int g = 0; g < 4; ++g)
#pragma unroll
        for (int ks = 0; ks < 4; ++ks)
            whf[g][ks] = *(const half8*)(whh_p + ((size_t)((g * 8 + ut) * 4 + ks) * 64 + L) * 8);

    __syncthreads();    // Pt visible to all waves

    // h scatter address components (A-fragment layout for unit u, window m)
    const int ks_h = ut >> 1;
    const int qp   = (ut & 1) * 2 + (ln >> 3);

    float cst[2][4] = {{0.f, 0.f, 0.f, 0.f}, {0.f, 0.f, 0.f, 0.f}};
    float mv = -FLT_MAX;

    // ---- steps 0..5, two independent sub-tiles per barrier interval ----
    for (int st = 0; st < FWn; ++st) {
        if (st > 0) __syncthreads();        // prev step's h scatter visible
#pragma unroll
        for (int sub = 0; sub < 2; ++sub) {
            f32x4 acc[4];                   // [gate] over r
#pragma unroll
            for (int r = 0; r < 4; ++r) {
                half4 pv = *(const half4*)&Pt[(sub * 16 + q * 4 + r + st) * PSTRIDE + u * 4];
                acc[0][r] = (float)pv[0]; acc[1][r] = (float)pv[1];
                acc[2][r] = (float)pv[2]; acc[3][r] = (float)pv[3];
            }
            if (st > 0) {
                const _Float16* hb = hsA[(st + 1) & 1][sub];   // h(st-1)
#pragma unroll
                for (int ks = 0; ks < 4; ++ks) {
                    half8 ah = *(const half8*)(hb + (ks * 64 + L) * 8);
#pragma unroll
                    for (int g = 0; g < 4; ++g)
                        acc[g] = __builtin_amdgcn_mfma_f32_16x16x32_f16(ah, whf[g][ks], acc[g], 0, 0, 0);
                }
            }
            _Float16* buf = hsA[st & 1][sub];
#pragma unroll
            for (int r = 0; r < 4; ++r) {
                // pre-activations already scaled: i',f',o' by log2e; g'' by 2log2e
                float a  = __builtin_amdgcn_exp2f(-acc[0][r]);   // exp(-i)
                float cf = __builtin_amdgcn_exp2f(-acc[1][r]);   // exp(-f)
                float bb = __builtin_amdgcn_exp2f(-acc[2][r]);   // exp(-2g)
                float co = __builtin_amdgcn_exp2f(-acc[3][r]);   // exp(-o)
                float ft  = __builtin_amdgcn_rcpf(1.0f + cf);                    // sig(f)
                float itg = (1.0f - bb) * __builtin_amdgcn_rcpf((1.0f + a) * (1.0f + bb)); // sig(i)*tanh(g)
                float cc  = fmaf(cst[sub][r], ft, itg);
                cst[sub][r] = cc;
                float d  = __builtin_amdgcn_exp2f(-LOG2E2 * cc);                 // exp(-2c)
                float hv = (1.0f - d) * __builtin_amdgcn_rcpf((1.0f + co) * (1.0f + d));   // sig(o)*tanh(c)
                if (st < FWn - 1) {
                    buf[ks_h * 512 + (qp * 16 + q * 4 + r) * 8 + j8] = (_Float16)hv;
                } else {
                    const int w = w0 + sub * 16 + q * 4 + r;
                    mv = fmaxf(mv, (w < Wn) ? hv : -FLT_MAX);
                }
            }
        }
    }

    // ---- reduce max across q; q==0 lanes atomically fold into feat[b][u] ----
    mv = fmaxf(mv, __shfl_xor(mv, 16));
    mv = fmaxf(mv, __shfl_xor(mv, 32));
    if (q == 0) {
        // order-preserving encode: monotone in float order, all real keys > 0
        unsigned bits = __float_as_uint(mv);
        unsigned key  = (bits & 0x80000000u) ? ~bits : (bits | 0x80000000u);
        atomicMax(featk + b * 128 + u, key);
    }

    // ---- fused FC epilogue: last tile-block of batch b does the 128->2 FC ----
    // NO __threadfence (R21 regression): __syncthreads' vmcnt(0) drain is the
    // release — the atomicMax ops above have completed at the device coherent
    // point before t==0's atomicAdd can issue.
    float* red  = (float*)hsA;           // red[0..3] (hsA dead after step 5)
    int*   lastf = (int*)hsA + 4;
    __syncthreads();                     // drains all waves' atomicMax (vmcnt 0)
    if (t == 0)
        *lastf = (atomicAdd(cnt + b, 1u) == NTILE - 1);
    __syncthreads();
    if (*lastf) {
        float v0 = 0.f, v1 = 0.f;
        if (t < 128) {
            // coherent-point read of other XCDs' atomicMax results
            unsigned key = atomicOr(featk + b * 128 + t, 0u);
            const float m = __uint_as_float((key & 0x80000000u) ? (key & 0x7FFFFFFFu) : ~key);
            v0 = m * fc_w[t];
            v1 = m * fc_w[128 + t];
#pragma unroll
            for (int off = 1; off < 64; off <<= 1) {
                v0 += __shfl_xor(v0, off);
                v1 += __shfl_xor(v1, off);
            }
        }
        __syncthreads();                 // red[] safe to overwrite
        if (t < 128 && (t & 63) == 0) { red[(t >> 6) * 2] = v0; red[(t >> 6) * 2 + 1] = v1; }
        __syncthreads();
        if (t == 0) {
            out[b * 2 + 0] = red[0] + red[2] + fc_b[0];
            out[b * 2 + 1] = red[1] + red[3] + fc_b[1];
        }
    }
}

// ---------------------------------------------------------------------------
extern "C" void kernel_launch(void* const* d_in, const int* in_sizes, int n_in,
                              void* d_out, int out_size, void* d_ws, size_t ws_size,
                              hipStream_t stream)
{
    const int*   inputs = (const int*)d_in[0];
    // d_in[1] = lengths : unused by the reference
    const float* embed  = (const float*)d_in[2];
    const float* w_ih   = (const float*)d_in[3];
    const float* w_hh   = (const float*)d_in[4];
    const float* b_ih   = (const float*)d_in[5];
    const float* b_hh   = (const float*)d_in[6];
    const float* fc_w   = (const float*)d_in[7];
    const float* fc_b   = (const float*)d_in[8];
    float* out = (float*)d_out;

    // workspace: featk (8192 u32) | cnt (64 u32) | wih_p, whh_p (128 KiB each)
    unsigned* featk = (unsigned*)d_ws;
    unsigned* cnt   = featk + Bn * 128;
    _Float16* wih_p = (_Float16*)(cnt + Bn);
    _Float16* whh_p = wih_p + 65536;

    pack_w_kernel<<<dim3(64), 256, 0, stream>>>(w_ih, w_hh, wih_p, whh_p, featk);
    lstm_kernel<<<dim3(Bn * NTILE), 512, 0, stream>>>(inputs, embed, wih_p, whh_p,
                                                      b_ih, b_hh, featk, cnt,
                                                      fc_w, fc_b, out);
}

// Round 15
// 135.160 us; speedup vs baseline: 1.7651x; 1.0306x over previous
//
#include <hip/hip_runtime.h>
#include <math.h>
#include <float.h>

// Problem constants (fixed by the reference)
#define Bn   64
#define Sn   512
#define FWn  6
#define Wn   507     // S - FW + 1
#define WT   32      // windows per block (2 sub-tiles of 16) — R12 geometry
#define NTILE 16     // 507 windows -> 16 tiles of 32

#define PROWS   37    // projection rows per block (32 windows + FW-1)
#define PSTRIDE 512   // fp16 elems per Pt row (1024 B); phase-conflict-free (R10)

#define LOG2E  1.4426950408889634f
#define LOG2E2 2.8853900817779268f

typedef __attribute__((ext_vector_type(8))) _Float16 half8;
typedef __attribute__((ext_vector_type(4))) _Float16 half4;
typedef __attribute__((ext_vector_type(4))) float f32x4;

// ---------------------------------------------------------------------------
// Kernel 0: pack w_ih and w_hh into fp16 B-fragment order for
// mfma_f32_16x16x32_f16, PRE-SCALED by log2e (gates i,f,o) / 2log2e (gate g).
// Vectorized: 4 elems/thread (float4 in, half4 out). 16384 threads = 64 blocks
// (grid MUST be 64 — R19's 128-block overrun corrupted whh_p).
// Also zero-inits featk (8192 keys) — no extra launch.
// ---------------------------------------------------------------------------
__global__ void __launch_bounds__(256)
pack_w_kernel(const float* __restrict__ w_ih, const float* __restrict__ w_hh,
              _Float16* __restrict__ wih_p, _Float16* __restrict__ whh_p,
              unsigned* __restrict__ featk)
{
    const int i4 = blockIdx.x * 256 + threadIdx.x;   // 0..16383 (4 elems each)
    if (i4 < Bn * 128) featk[i4] = 0;                // encoded floor (< any real key)
    const int e  = i4 * 4;                           // 0..65532
    const int j0 = e & 4;
    const int L  = (e >> 3) & 63;
    const int ks = (e >> 9) & 3;
    const int nt = e >> 11;                          // 0..31
    const int row = nt * 16 + (L & 15);
    const int col = ks * 32 + (L >> 4) * 8 + j0;
    const float sc = ((nt >> 3) == 2) ? LOG2E2 : LOG2E;   // gate g doubled
    float4 a = *(const float4*)(w_ih + row * 128 + col);
    float4 b = *(const float4*)(w_hh + row * 128 + col);
    half4 pa, pb;
    pa[0] = (_Float16)(sc * a.x); pa[1] = (_Float16)(sc * a.y);
    pa[2] = (_Float16)(sc * a.z); pa[3] = (_Float16)(sc * a.w);
    pb[0] = (_Float16)(sc * b.x); pb[1] = (_Float16)(sc * b.y);
    pb[2] = (_Float16)(sc * b.z); pb[3] = (_Float16)(sc * b.w);
    *(half4*)(wih_p + e) = pa;
    *(half4*)(whh_p + e) = pb;
}

// ---------------------------------------------------------------------------
// Kernel 1 (fused MFMA LSTM) — R15's verified-best body (58 us, reproduced
// 4x). SESSION ADJUDICATION (R10..R22): the binding constraint is the
// barrier-serialized 6-step recurrence at the allocator's 64-arch-VGPR pin.
// Neutral-or-worse, all counter-verified:
//   - occupancy up via LDS shave or VGPR cap (R10/R11): slower or neutral;
//   - balanced generations, WT=16 (R14): neutral;
//   - register-resident P via shuffles (R13): scratch catastrophe;
//   - AGPR-resident whh, B-operand asm (R16): works, but 1 blk/CU loses more;
//   - AGPR C/D asm (R17): numerically wrong (missing hazard waits);
//   - device-scope fence in epilogue (R21): cross-XCD L2 flush, -2.8x;
//   - fused FC epilogue, no fence (R22): correct but +3.5 us on lstm > 1 us
//     launch saved.
// Keepers: fused exp2 activations w/ pre-scaled weights (-6 us), streamed
// whh at the 64-VGPR pin, 3 blocks/CU, atomicMax feat fold.
// grid 64*16, block 512.
// ---------------------------------------------------------------------------
__global__ void __launch_bounds__(512)
__attribute__((amdgpu_waves_per_eu(4, 4)))
lstm_kernel(const int* __restrict__ inputs, const float* __restrict__ embed,
            const _Float16* __restrict__ wih_p, const _Float16* __restrict__ whh_p,
            const float* __restrict__ b_ih, const float* __restrict__ b_hh,
            unsigned* __restrict__ featk)
{
    __shared__ __align__(16) _Float16 Pt[PROWS * PSTRIDE];  // 37 KiB
    __shared__ __align__(16) _Float16 hsA[2][2][2048];      // 16 KiB
    const int t    = threadIdx.x;
    const int L    = t & 63;
    const int ut   = t >> 6;          // wave index = unit-tile 0..7
    const int b    = blockIdx.x >> 4;
    const int tile = blockIdx.x & 15;
    const int w0   = tile * WT;
    const int q  = L >> 4;
    const int ln = L & 15;
    const int j8 = L & 7;
    const int u  = ut * 16 + ln;      // this lane's hidden unit (B n-index)

    // ---- phase 1: x-proj (3 m-tiles = rows 0..47, stores clamped to 37) ----
    {
        f32x4 accx[3][4];   // [mt][gate], init with folded bias
#pragma unroll
        for (int g = 0; g < 4; ++g) {
            const float sc = (g == 2) ? LOG2E2 : LOG2E;
            const float bg = sc * (b_ih[g * 128 + u] + b_hh[g * 128 + u]);
            accx[0][g] = (f32x4){bg, bg, bg, bg};
            accx[1][g] = accx[0][g];
            accx[2][g] = accx[0][g];
        }
        int tok[3];
#pragma unroll
        for (int mt = 0; mt < 3; ++mt) {
            int s = w0 + mt * 16 + ln; s = s < 511 ? s : 511;  // clamp (masked at max)
            tok[mt] = inputs[b * Sn + s];
        }
#pragma unroll
        for (int ks = 0; ks < 4; ++ks) {
            half8 ax[3];
#pragma unroll
            for (int mt = 0; mt < 3; ++mt) {
                const float* er = embed + (size_t)tok[mt] * 128 + ks * 32 + q * 8;
                float4 e0 = *(const float4*)er;
                float4 e1 = *(const float4*)(er + 4);
                half8 a;
                a[0] = (_Float16)e0.x; a[1] = (_Float16)e0.y;
                a[2] = (_Float16)e0.z; a[3] = (_Float16)e0.w;
                a[4] = (_Float16)e1.x; a[5] = (_Float16)e1.y;
                a[6] = (_Float16)e1.z; a[7] = (_Float16)e1.w;
                ax[mt] = a;
            }
#pragma unroll
            for (int g = 0; g < 4; ++g) {
                half8 bw = *(const half8*)(wih_p + ((size_t)((g * 8 + ut) * 4 + ks) * 64 + L) * 8);
#pragma unroll
                for (int mt = 0; mt < 3; ++mt)
                    accx[mt][g] = __builtin_amdgcn_mfma_f32_16x16x32_f16(ax[mt], bw, accx[mt][g], 0, 0, 0);
            }
        }
        // store gate-interleaved fp16 Pt rows (predicated to 37 rows)
#pragma unroll
        for (int mt = 0; mt < 3; ++mt)
#pragma unroll
            for (int r = 0; r < 4; ++r) {
                const int sl = mt * 16 + q * 4 + r;
                if (sl < PROWS) {
                    half4 o;
                    o[0] = (_Float16)accx[mt][0][r];
                    o[1] = (_Float16)accx[mt][1][r];
                    o[2] = (_Float16)accx[mt][2][r];
                    o[3] = (_Float16)accx[mt][3][r];
                    *(half4*)&Pt[sl * PSTRIDE + u * 4] = o;
                }
            }
    }

    // w_hh B-fragments, source-hoisted (allocator streams from L2 at its
    // 64-VGPR pin — benched fastest across R12..R18).
    half8 whf[4][4];    // [gate][ks]
#pragma unroll
    for (int g = 0; g < 4; ++g)
#pragma unroll
        for (int ks = 0; ks < 4; ++ks)
            whf[g][ks] = *(const half8*)(whh_p + ((size_t)((g * 8 + ut) * 4 + ks) * 64 + L) * 8);

    __syncthreads();    // Pt visible to all waves

    // h scatter address components (A-fragment layout for unit u, window m)
    const int ks_h = ut >> 1;
    const int qp   = (ut & 1) * 2 + (ln >> 3);

    float cst[2][4] = {{0.f, 0.f, 0.f, 0.f}, {0.f, 0.f, 0.f, 0.f}};
    float mv = -FLT_MAX;

    // ---- steps 0..5, two independent sub-tiles per barrier interval ----
    for (int st = 0; st < FWn; ++st) {
        if (st > 0) __syncthreads();        // prev step's h scatter visible
#pragma unroll
        for (int sub = 0; sub < 2; ++sub) {
            f32x4 acc[4];                   // [gate] over r
#pragma unroll
            for (int r = 0; r < 4; ++r) {
                half4 pv = *(const half4*)&Pt[(sub * 16 + q * 4 + r + st) * PSTRIDE + u * 4];
                acc[0][r] = (float)pv[0]; acc[1][r] = (float)pv[1];
                acc[2][r] = (float)pv[2]; acc[3][r] = (float)pv[3];
            }
            if (st > 0) {
                const _Float16* hb = hsA[(st + 1) & 1][sub];   // h(st-1)
#pragma unroll
                for (int ks = 0; ks < 4; ++ks) {
                    half8 ah = *(const half8*)(hb + (ks * 64 + L) * 8);
#pragma unroll
                    for (int g = 0; g < 4; ++g)
                        acc[g] = __builtin_amdgcn_mfma_f32_16x16x32_f16(ah, whf[g][ks], acc[g], 0, 0, 0);
                }
            }
            _Float16* buf = hsA[st & 1][sub];
#pragma unroll
            for (int r = 0; r < 4; ++r) {
                // pre-activations already scaled: i',f',o' by log2e; g'' by 2log2e
                float a  = __builtin_amdgcn_exp2f(-acc[0][r]);   // exp(-i)
                float cf = __builtin_amdgcn_exp2f(-acc[1][r]);   // exp(-f)
                float bb = __builtin_amdgcn_exp2f(-acc[2][r]);   // exp(-2g)
                float co = __builtin_amdgcn_exp2f(-acc[3][r]);   // exp(-o)
                float ft  = __builtin_amdgcn_rcpf(1.0f + cf);                    // sig(f)
                float itg = (1.0f - bb) * __builtin_amdgcn_rcpf((1.0f + a) * (1.0f + bb)); // sig(i)*tanh(g)
                float cc  = fmaf(cst[sub][r], ft, itg);
                cst[sub][r] = cc;
                float d  = __builtin_amdgcn_exp2f(-LOG2E2 * cc);                 // exp(-2c)
                float hv = (1.0f - d) * __builtin_amdgcn_rcpf((1.0f + co) * (1.0f + d));   // sig(o)*tanh(c)
                if (st < FWn - 1) {
                    buf[ks_h * 512 + (qp * 16 + q * 4 + r) * 8 + j8] = (_Float16)hv;
                } else {
                    const int w = w0 + sub * 16 + q * 4 + r;
                    mv = fmaxf(mv, (w < Wn) ? hv : -FLT_MAX);
                }
            }
        }
    }

    // ---- reduce max across q; q==0 lanes atomically fold into feat[b][u] ----
    mv = fmaxf(mv, __shfl_xor(mv, 16));
    mv = fmaxf(mv, __shfl_xor(mv, 32));
    if (q == 0) {
        // order-preserving encode: monotone in float order, all real keys > 0
        unsigned bits = __float_as_uint(mv);
        unsigned key  = (bits & 0x80000000u) ? ~bits : (bits | 0x80000000u);
        atomicMax(featk + b * 128 + u, key);
    }
}

// ---------------------------------------------------------------------------
// Kernel 2: decode feat keys; out[b][c] = feat . fc_w[c] + fc_b[c]
// grid 64, block 128. (32 KB read; launch costs ~1 us — cheaper than fusing,
// R22 measured.)
// ---------------------------------------------------------------------------
__global__ void __launch_bounds__(128)
final_kernel(const unsigned* __restrict__ featk, const float* __restrict__ fc_w,
             const float* __restrict__ fc_b, float* __restrict__ out)
{
    const int b = blockIdx.x;
    const int u = threadIdx.x;
    const unsigned key = featk[b * 128 + u];
    const float m = __uint_as_float((key & 0x80000000u) ? (key & 0x7FFFFFFFu) : ~key);
    float v0 = m * fc_w[u];
    float v1 = m * fc_w[128 + u];
#pragma unroll
    for (int off = 1; off < 64; off <<= 1) {
        v0 += __shfl_xor(v0, off);
        v1 += __shfl_xor(v1, off);
    }
    __shared__ float red[2][2];
    if ((u & 63) == 0) { red[u >> 6][0] = v0; red[u >> 6][1] = v1; }
    __syncthreads();
    if (u == 0) {
        out[b * 2 + 0] = red[0][0] + red[1][0] + fc_b[0];
        out[b * 2 + 1] = red[0][1] + red[1][1] + fc_b[1];
    }
}

// ---------------------------------------------------------------------------
extern "C" void kernel_launch(void* const* d_in, const int* in_sizes, int n_in,
                              void* d_out, int out_size, void* d_ws, size_t ws_size,
                              hipStream_t stream)
{
    const int*   inputs = (const int*)d_in[0];
    // d_in[1] = lengths : unused by the reference
    const float* embed  = (const float*)d_in[2];
    const float* w_ih   = (const float*)d_in[3];
    const float* w_hh   = (const float*)d_in[4];
    const float* b_ih   = (const float*)d_in[5];
    const float* b_hh   = (const float*)d_in[6];
    const float* fc_w   = (const float*)d_in[7];
    const float* fc_b   = (const float*)d_in[8];
    float* out = (float*)d_out;

    // workspace: featk (8192 u32) | wih_p, whh_p (128 KiB each)
    unsigned* featk = (unsigned*)d_ws;
    _Float16* wih_p = (_Float16*)(featk + Bn * 128);
    _Float16* whh_p = wih_p + 65536;

    pack_w_kernel<<<dim3(64), 256, 0, stream>>>(w_ih, w_hh, wih_p, whh_p, featk);
    lstm_kernel<<<dim3(Bn * NTILE), 512, 0, stream>>>(inputs, embed, wih_p, whh_p,
                                                      b_ih, b_hh, featk);
    final_kernel<<<dim3(Bn), 128, 0, stream>>>(featk, fc_w, fc_b, out);
}